// Round 12
// baseline (323.810 us; speedup 1.0000x reference)
//
#include <hip/hip_runtime.h>
#include <limits.h>

// Problem constants (fixed by setup_inputs):
//   xyz (B,N,3) f32, new_xyz (B,P,3) f32, features (B,C,N) f32
//   out = concat([grouped_xyz - center, grouped_features], ch) -> (B, 3+C, P, S)
#define BB 2
#define NN 16384
#define PP 4096
#define CC 64
#define SS 32
#define R2 0.01f
#define OUTCH (3 + CC)
#define GRES 10
#define NCELL 1000   // 10x10x10, cell size 0.1 == radius
#define TILE 128     // samples per block (4 queries x 32)
#define BINBLK 128   // bin_all blocks — co-resident on 256 CUs
// ATTRIBUTION reps: push every kernel above the ~47us profile fill floor.
#define T_REPS 12
#define B_REPS 4
#define Q_REPS 4
#define G_REPS 3

__device__ __forceinline__ int cell_of(float v) {
  int q = (int)(v * 10.0f);  // v in [0,1): floor
  return q < 0 ? 0 : (q > GRES - 1 ? GRES - 1 : q);
}
__device__ __forceinline__ int cell_clamp_floor(float v) {
  int q = (int)floorf(v * 10.0f);
  return q < 0 ? 0 : (q > GRES - 1 ? GRES - 1 : q);
}

// --------------------------------------------------------------------------
// D1: Transpose features (B,C,N)->(B,N,C), repped x12. z0 asm defeats
// cross-rep CSE; every rep rewrites identical values (idempotent). Block
// (0,0) zeroes hist/fill/done each rep (stream-ordered before bin_all).
// --------------------------------------------------------------------------
__global__ __launch_bounds__(256) void transpose_feat_kernel(
    const float* __restrict__ feat, float* __restrict__ featT,
    int* __restrict__ zeroRegion) {
  __shared__ float tile[64][65];
  const int n0 = blockIdx.x * 64;
  const int b = blockIdx.y;
  const int jn = threadIdx.x & 63;
  const int g4 = threadIdx.x >> 6;
  const float* fb = feat + (size_t)b * CC * NN;
  float* ft = featT + ((size_t)b * NN + n0) * CC;

  for (int rep = 0; rep < T_REPS; ++rep) {
    int z0 = 0;
    asm volatile("" : "+v"(z0));  // opaque zero: forces real reloads per rep

    if (blockIdx.x == 0 && blockIdx.y == 0) {
      for (int k = threadIdx.x; k < 2 * BB * NCELL + 8; k += 256)
        zeroRegion[k + z0] = 0;
    }
#pragma unroll
    for (int k = 0; k < 16; ++k) {
      const int c = g4 * 16 + k;
      tile[c][jn] = fb[(size_t)c * NN + n0 + jn + z0];
    }
    __syncthreads();
#pragma unroll
    for (int k = 0; k < 16; ++k) {
      const int j = g4 * 16 + k;
      ft[(size_t)j * CC + jn] = tile[jn][j + z0];
    }
    __syncthreads();  // LDS reuse safe across reps
  }
}

// --------------------------------------------------------------------------
// D2: ONE-DISPATCH binning, repped x4 with generation-counted grid barriers.
// Each rep: [bar] zero hist/fill slice -> [bar] hist atomics -> [bar] scan
// -> publish -> scatter. doneG is zeroed by D1 every call (replay-safe);
// barrier k waits doneG >= k*BINBLK. 128 blocks co-resident => no deadlock.
// Within-cell scatter order varies run-to-run but downstream depends only on
// the SET of in-ball indices (bitmap) => deterministic output.
// --------------------------------------------------------------------------
__global__ __launch_bounds__(256) void bin_all_kernel(
    const float* __restrict__ xyz, int* __restrict__ histG,
    int* __restrict__ doneG, int* __restrict__ cellStartG,
    float4* __restrict__ sorted4) {
  __shared__ int cstart[NCELL];
  __shared__ int wsum[4];
  int* fillG = histG + BB * NCELL;  // contiguous by layout
  const int blk = blockIdx.x;
  const int b = blk >> 6;
  const int t = threadIdx.x;
  const int lane = t & 63;
  const int w = t >> 6;
  const int i = (blk & 63) * 256 + t;

  const float* p = xyz + ((size_t)b * NN + i) * 3;
  const float x = p[0], y = p[1], z = p[2];
  const int c = (cell_of(z) * GRES + cell_of(y)) * GRES + cell_of(x);

  int gen = 0;
  const int zi = blk * 256 + t;

  for (int rep = 0; rep < B_REPS; ++rep) {
    if (rep > 0) {  // wait for all scatters of prev rep before re-zeroing
      __threadfence();
      __syncthreads();
      ++gen;
      if (t == 0) {
        atomicAdd(doneG, 1);
        while (__hip_atomic_load(doneG, __ATOMIC_ACQUIRE,
                                 __HIP_MEMORY_SCOPE_AGENT) < gen * BINBLK) {}
      }
      __syncthreads();
    }
    // zero hist+fill (4000 ints across 32768 threads)
    if (zi < 2 * BB * NCELL) histG[zi] = 0;
    __threadfence();
    __syncthreads();
    ++gen;
    if (t == 0) {
      atomicAdd(doneG, 1);
      while (__hip_atomic_load(doneG, __ATOMIC_ACQUIRE,
                               __HIP_MEMORY_SCOPE_AGENT) < gen * BINBLK) {}
    }
    __syncthreads();

    // histogram
    atomicAdd(histG + b * NCELL + c, 1);
    __threadfence();
    __syncthreads();
    ++gen;
    if (t == 0) {
      atomicAdd(doneG, 1);
      while (__hip_atomic_load(doneG, __ATOMIC_ACQUIRE,
                               __HIP_MEMORY_SCOPE_AGENT) < gen * BINBLK) {}
    }
    __syncthreads();

    // redundant per-block scan
    int v0 = 0, v1 = 0, v2 = 0, v3 = 0, s = 0;
    if (t < 250) {
      const int base = b * NCELL + t * 4;
      v0 = __hip_atomic_load(histG + base + 0, __ATOMIC_RELAXED, __HIP_MEMORY_SCOPE_AGENT);
      v1 = __hip_atomic_load(histG + base + 1, __ATOMIC_RELAXED, __HIP_MEMORY_SCOPE_AGENT);
      v2 = __hip_atomic_load(histG + base + 2, __ATOMIC_RELAXED, __HIP_MEMORY_SCOPE_AGENT);
      v3 = __hip_atomic_load(histG + base + 3, __ATOMIC_RELAXED, __HIP_MEMORY_SCOPE_AGENT);
      s = v0 + v1 + v2 + v3;
    }
    int incl = s;
#pragma unroll
    for (int d = 1; d < 64; d <<= 1) {
      const int u = __shfl_up(incl, d);
      if (lane >= d) incl += u;
    }
    if (lane == 63) wsum[w] = incl;
    __syncthreads();
    int pre = 0;
#pragma unroll
    for (int k = 0; k < 4; ++k) pre += (k < w) ? wsum[k] : 0;
    if (t < 250) {
      int run = pre + incl - s;
      cstart[t * 4 + 0] = run; run += v0;
      cstart[t * 4 + 1] = run; run += v1;
      cstart[t * 4 + 2] = run; run += v2;
      cstart[t * 4 + 3] = run;
    }
    __syncthreads();

    if ((blk & 63) == 0) {
      if (t < 250) {
#pragma unroll
        for (int k = 0; k < 4; ++k)
          cellStartG[b * 1001 + t * 4 + k] = cstart[t * 4 + k];
      }
      if (t == 0) cellStartG[b * 1001 + NCELL] = NN;
    }

    // scatter
    const int r = atomicAdd(fillG + b * NCELL + c, 1);
    const int pos = cstart[c] + r;
    float4 vv;
    vv.x = x; vv.y = y; vv.z = z; vv.w = __int_as_float(i);
    sorted4[(size_t)b * NN + pos] = vv;
  }
}

// --------------------------------------------------------------------------
// D3: STANDALONE ball query, repped x4 (asm identity on cx/cy/cz per rep —
// R7-proven). Algorithm identical to passing R8-R11: sphere-tight rows,
// flattened ranges, pipelined candidate loop, per-wave LDS bitmap, ordered
// emit. Writes ushort indices to ws (idxU) — pure function => idempotent.
// --------------------------------------------------------------------------
__global__ __launch_bounds__(256) void ball_query_kernel(
    const float4* __restrict__ sorted4, const int* __restrict__ cellStart,
    const float* __restrict__ new_xyz, ushort* __restrict__ idxU) {
#pragma clang fp contract(off)
  __shared__ unsigned bmAll[4 * 576];  // 9216 B
  const int widx = threadIdx.x >> 6;
  const int lane = threadIdx.x & 63;
  const int wave = blockIdx.x * 4 + widx;
  const int b = wave >> 12;
  unsigned* bm = bmAll + widx * 576;
  ushort* myout = idxU + wave * SS;

  float cx = new_xyz[wave * 3 + 0];
  float cy = new_xyz[wave * 3 + 1];
  float cz = new_xyz[wave * 3 + 2];
  const float4* __restrict__ sb = sorted4 + (size_t)b * NN;
  const int* __restrict__ csb = cellStart + b * 1001;

  for (int rep = 0; rep < Q_REPS; ++rep) {
    asm volatile("" : "+v"(cx), "+v"(cy), "+v"(cz));  // blocks cross-rep CSE

#pragma unroll
    for (int k = 0; k < 9; ++k) bm[k * 64 + lane] = 0;

    const float mg = 0.1f + 1e-5f;
    const int loy = cell_clamp_floor(cy - mg), hiy = cell_clamp_floor(cy + mg);
    const int loz = cell_clamp_floor(cz - mg), hiz = cell_clamp_floor(cz + mg);
    const int ny = hiy - loy + 1;
    const int nz = hiz - loz + 1;
    const int nr = nz * ny;  // 1..9 (z,y) rows

    int s_l = 0, len_l = 0;
    if (lane < nr) {
      int zi, yi;
      if (ny == 1) { zi = lane; yi = 0; }
      else if (ny == 2) { zi = lane >> 1; yi = lane & 1; }
      else { zi = (lane * 11) >> 5; yi = lane - zi * 3; }  // lane/3, lane<9
      const int zc = loz + zi, yc = loy + yi;
      const float y0 = yc * 0.1f, z0 = zc * 0.1f;
      const float dymin = fmaxf(fmaxf(y0 - cy, cy - (y0 + 0.1f)), 0.0f);
      const float dzmin = fmaxf(fmaxf(z0 - cz, cz - (z0 + 0.1f)), 0.0f);
      const float rem = mg * mg - dymin * dymin - dzmin * dzmin;
      if (rem > 0.0f) {
        const float dxa = sqrtf(rem) * 1.0000002f + 1e-7f;  // round-up guard
        const int lxr = cell_clamp_floor(cx - dxa);
        const int hxr = cell_clamp_floor(cx + dxa);
        const int c0 = (zc * GRES + yc) * GRES + lxr;
        s_l = csb[c0];
        len_l = csb[c0 + (hxr - lxr + 1)] - s_l;
      }
    }
    int incl = len_l;
#pragma unroll
    for (int d = 1; d <= 8; d <<= 1) {
      const int v = __shfl_up(incl, d);
      if (lane >= d) incl += v;
    }
    const int T = __shfl(incl, nr - 1);
    const int Lx = incl - len_l;

    int Lk[9], Sk[9];
#pragma unroll
    for (int k = 0; k < 9; ++k) {
      Lk[k] = __shfl(Lx, k);
      Sk[k] = __shfl(s_l, k);
    }

    auto flat_load = [&](int g) -> float4 {
      int L = Lk[0], S = Sk[0];
#pragma unroll
      for (int k = 1; k < 9; ++k) {
        const bool cge = g >= Lk[k];
        L = cge ? Lk[k] : L;
        S = cge ? Sk[k] : S;
      }
      return sb[S + (g - L)];
    };

    const int nIt = (T + 63) >> 6;
    float4 cur = {};
    if (lane < T) cur = flat_load(lane);
    for (int it = 0; it < nIt; ++it) {
      float4 nxt = cur;
      const int gn = (it + 1) * 64 + lane;
      if (gn < T) nxt = flat_load(gn);
      const int g = it * 64 + lane;
      if (g < T) {
        const float dx = cx - cur.x;
        const float dy = cy - cur.y;
        const float dz = cz - cur.z;
        const float a = dx * dx + dy * dy;
        const float d2 = a + dz * dz;
        if (d2 < R2) {
          const int orig = __float_as_int(cur.w);
          const int wi = orig >> 5;
          atomicOr(&bm[(wi >> 3) * 9 + (wi & 7)], 1u << (orig & 31));
        }
      }
      cur = nxt;
    }
    __threadfence_block();

    unsigned wv[8];
    int c = 0;
    int fi = INT_MAX;
#pragma unroll
    for (int k = 0; k < 8; ++k) {
      wv[k] = bm[lane * 9 + k];
      c += (int)__popc(wv[k]);
      if (fi == INT_MAX && wv[k])
        fi = lane * 256 + k * 32 + (int)__builtin_ctz(wv[k]);
    }

    int incl2 = c;
#pragma unroll
    for (int d = 1; d < 64; d <<= 1) {
      const int t = __shfl_up(incl2, d);
      if (lane >= d) incl2 += t;
    }
    const int E = incl2 - c;
    const int total = __shfl(incl2, 63);

    const unsigned long long nb = __ballot(c > 0);
    int fc = 0;
    if (nb) fc = __shfl(fi, (int)__builtin_ctzll(nb));

    int s = E;
    if (s < SS) {
#pragma unroll
      for (int k = 0; k < 8; ++k) {
        unsigned ww = wv[k];
        while (ww && s < SS) {
          const int bpos = (int)__builtin_ctz(ww);
          ww &= ww - 1;
          myout[s++] = (ushort)(lane * 256 + k * 32 + bpos);
        }
        if (s >= SS) break;
      }
    }
    for (int s2 = total + lane; s2 < SS; s2 += 64) myout[s2] = (ushort)fc;
  }
}

// --------------------------------------------------------------------------
// D4: STANDALONE gather + group (R2/R3-proven body), repped x3. idx comes
// from ws (idxU) -> kernel is a pure function => reps idempotent. z0 asm
// defeats cross-rep load CSE.
// --------------------------------------------------------------------------
__global__ __launch_bounds__(256) void group_kernel_t(
    const float* __restrict__ xyz, const float* __restrict__ new_xyz,
    const float* __restrict__ featT, const ushort* __restrict__ idxU,
    float* __restrict__ out) {
  __shared__ float lds[TILE * 65];
  __shared__ int idxsm[TILE];
  const int base = blockIdx.x * TILE;
  const int b = base >> 17;  // P*S = 2^17
  const int t = threadIdx.x;
  const size_t PS = (size_t)PP * SS;

  if (t < TILE) idxsm[t] = (int)idxU[base + t];
  __syncthreads();

  const float4* ftb = (const float4*)(featT + (size_t)b * NN * CC);
  float* ob3 = out + (size_t)b * OUTCH * PS + 3 * PS + ((size_t)base & (PS - 1));

  for (int rep = 0; rep < G_REPS; ++rep) {
    int z0 = 0;
    asm volatile("" : "+v"(z0));  // opaque zero

#pragma unroll
    for (int k = 0; k < 8; ++k) {
      const int u = k * 256 + t + z0;
      const int r = u >> 4;
      const int q = u & 15;
      const int v = idxsm[r];
      const float4 val = ftb[(size_t)v * 16 + q];
      float* dst = &lds[r * 65 + q * 4];
      dst[0] = val.x; dst[1] = val.y; dst[2] = val.z; dst[3] = val.w;
    }
    __syncthreads();

    if (t < TILE) {
      const int g = base + t;
      const int v = idxsm[t] + z0;
      const int p = (g >> 5) & (PP - 1);
      const float* xr = xyz + ((size_t)b * NN + v) * 3;
      const float* cr = new_xyz + (size_t)(b * PP + p) * 3;
      const size_t ob = (size_t)b * OUTCH * PS + ((size_t)g & (PS - 1));
      out[ob + 0 * PS] = xr[0] - cr[0];
      out[ob + 1 * PS] = xr[1] - cr[1];
      out[ob + 2 * PS] = xr[2] - cr[2];
    }

#pragma unroll
    for (int k = 0; k < 32; ++k) {
      const int u = k * 256 + t + z0;
      const int c2 = u >> 7;
      const int r = u & 127;
      ob3[(size_t)c2 * PS + r] = lds[r * 65 + c2];
    }
    __syncthreads();  // LDS reuse safe across reps
  }
}

extern "C" void kernel_launch(void* const* d_in, const int* in_sizes, int n_in,
                              void* d_out, int out_size, void* d_ws, size_t ws_size,
                              hipStream_t stream) {
  const float* xyz = (const float*)d_in[0];
  const float* new_xyz = (const float*)d_in[1];
  const float* feat = (const float*)d_in[2];
  float* out = (float*)d_out;

  // ws layout (9.42 MB, within the R5-proven 9.44 MB footprint):
  //   [featT 8.39MB][sorted4 0.5MB][idxU 0.5MB][cellStart 8008B]
  //   [hist 8000B][fill 8000B][done 32B]   (hist..done contiguous zero region)
  float* featT = (float*)d_ws;
  char* p = (char*)d_ws + (size_t)BB * NN * CC * sizeof(float);
  float4* sorted4 = (float4*)p;
  p += (size_t)BB * NN * sizeof(float4);
  ushort* idxU = (ushort*)p;
  p += (size_t)BB * PP * SS * sizeof(ushort);
  int* cellStart = (int*)p;
  p += (size_t)BB * 1001 * sizeof(int);
  int* hist = (int*)p;  // hist(2000) + fill(2000) + done(8) contiguous
  int* done = hist + 2 * BB * NCELL;

  transpose_feat_kernel<<<dim3(NN / 64, BB), 256, 0, stream>>>(feat, featT, hist);
  bin_all_kernel<<<BINBLK, 256, 0, stream>>>(xyz, hist, done, cellStart, sorted4);
  ball_query_kernel<<<(BB * PP) / 4, 256, 0, stream>>>(sorted4, cellStart,
                                                       new_xyz, idxU);
  group_kernel_t<<<(BB * PP * SS) / TILE, 256, 0, stream>>>(xyz, new_xyz, featT,
                                                            idxU, out);
}

// Round 13
// 82.957 us; speedup vs baseline: 3.9033x; 3.9033x over previous
//
#include <hip/hip_runtime.h>
#include <limits.h>

// Problem constants (fixed by setup_inputs):
//   xyz (B,N,3) f32, new_xyz (B,P,3) f32, features (B,C,N) f32
//   out = concat([grouped_xyz - center, grouped_features], ch) -> (B, 3+C, P, S)
#define BB 2
#define NN 16384
#define PP 4096
#define CC 64
#define SS 32
#define R2 0.01f
#define OUTCH (3 + CC)
#define GRES 10
#define NCELL 1000  // 10x10x10, cell size 0.1 == radius
#define TILE 128    // samples per block (4 queries x 32)

__device__ __forceinline__ int cell_of(float v) {
  int q = (int)(v * 10.0f);  // v in [0,1): floor
  return q < 0 ? 0 : (q > GRES - 1 ? GRES - 1 : q);
}
__device__ __forceinline__ int cell_clamp_floor(float v) {
  int q = (int)floorf(v * 10.0f);
  return q < 0 ? 0 : (q > GRES - 1 ? GRES - 1 : q);
}

// --------------------------------------------------------------------------
// D1: Transpose features (B,C,N)->(B,N,C). Block (0,0) zeroes hist+fill
// (stream-ordered before D2; replay-safe every call). R9-proven.
// --------------------------------------------------------------------------
__global__ __launch_bounds__(256) void transpose_feat_kernel(
    const float* __restrict__ feat, float* __restrict__ featT,
    int* __restrict__ zeroRegion) {
  __shared__ float tile[64][65];
  const int n0 = blockIdx.x * 64;
  const int b = blockIdx.y;
  const int jn = threadIdx.x & 63;
  const int g4 = threadIdx.x >> 6;

  if (blockIdx.x == 0 && blockIdx.y == 0) {
    for (int k = threadIdx.x; k < 2 * BB * NCELL + 8; k += 256) zeroRegion[k] = 0;
  }

  const float* fb = feat + (size_t)b * CC * NN;
#pragma unroll
  for (int k = 0; k < 16; ++k) {
    const int c = g4 * 16 + k;
    tile[c][jn] = fb[(size_t)c * NN + n0 + jn];
  }
  __syncthreads();
  float* ft = featT + ((size_t)b * NN + n0) * CC;
#pragma unroll
  for (int k = 0; k < 16; ++k) {
    const int j = g4 * 16 + k;
    ft[(size_t)j * CC + jn] = tile[jn][j];
  }
}

// --------------------------------------------------------------------------
// D2: histogram — 128 blocks, plain global atomics (hist pre-zeroed by D1).
// NO grid barrier (R12 measured ~15 us per resident-grid spin barrier).
// --------------------------------------------------------------------------
__global__ __launch_bounds__(256) void hist_kernel(const float* __restrict__ xyz,
                                                   int* __restrict__ hist) {
  const int i = blockIdx.x * 256 + threadIdx.x;  // [0, BB*NN)
  const int b = i >> 14;
  const float* p = xyz + (size_t)i * 3;
  const int c = (cell_of(p[2]) * GRES + cell_of(p[1])) * GRES + cell_of(p[0]);
  atomicAdd(hist + b * NCELL + c, 1);
}

// --------------------------------------------------------------------------
// D3: exclusive scan of the 1000-cell histogram, one block per batch,
// shfl-based (3 barriers total — NOT the 20-barrier ladder of R4/R8).
// This is R12's verified phase-B code as a standalone kernel.
// --------------------------------------------------------------------------
__global__ __launch_bounds__(256) void scan_fast_kernel(
    const int* __restrict__ hist, int* __restrict__ cellStartG) {
  __shared__ int wsum[4];
  const int b = blockIdx.x;
  const int t = threadIdx.x;
  const int lane = t & 63;
  const int w = t >> 6;

  int v0 = 0, v1 = 0, v2 = 0, v3 = 0, s = 0;
  if (t < 250) {
    const int base = b * NCELL + t * 4;
    v0 = hist[base + 0];
    v1 = hist[base + 1];
    v2 = hist[base + 2];
    v3 = hist[base + 3];
    s = v0 + v1 + v2 + v3;
  }
  int incl = s;
#pragma unroll
  for (int d = 1; d < 64; d <<= 1) {
    const int u = __shfl_up(incl, d);
    if (lane >= d) incl += u;
  }
  if (lane == 63) wsum[w] = incl;
  __syncthreads();
  int pre = 0;
#pragma unroll
  for (int k = 0; k < 4; ++k) pre += (k < w) ? wsum[k] : 0;
  if (t < 250) {
    int run = pre + incl - s;  // exclusive start of cell 4t
    cellStartG[b * 1001 + t * 4 + 0] = run; run += v0;
    cellStartG[b * 1001 + t * 4 + 1] = run; run += v1;
    cellStartG[b * 1001 + t * 4 + 2] = run; run += v2;
    cellStartG[b * 1001 + t * 4 + 3] = run;
  }
  if (t == 0) cellStartG[b * 1001 + NCELL] = NN;
}

// --------------------------------------------------------------------------
// D4: scatter — 128 blocks; cellStart read from global (L2-hot 8KB) + fill
// atomics (pre-zeroed by D1). Within-cell order is atomic-arrival
// (nondeterministic) but downstream depends only on the SET of in-ball
// indices (bitmap) => deterministic output.
// --------------------------------------------------------------------------
__global__ __launch_bounds__(256) void scatter_kernel(
    const float* __restrict__ xyz, const int* __restrict__ cellStartG,
    int* __restrict__ fill, float4* __restrict__ sorted4) {
  const int i = blockIdx.x * 256 + threadIdx.x;  // [0, BB*NN)
  const int b = i >> 14;
  const float* p = xyz + (size_t)i * 3;
  const float x = p[0], y = p[1], z = p[2];
  const int c = (cell_of(z) * GRES + cell_of(y)) * GRES + cell_of(x);
  const int r = atomicAdd(fill + b * NCELL + c, 1);
  const int pos = cellStartG[b * 1001 + c] + r;
  float4 v;
  v.x = x; v.y = y; v.z = z; v.w = __int_as_float(i & (NN - 1));
  sorted4[(size_t)b * NN + pos] = v;
}

// --------------------------------------------------------------------------
// D5: STANDALONE ball query (R12-proven, reps=1). Sphere-tight per-row
// x-ranges, flattened via shfl-scan, 2-deep pipelined candidate loop,
// per-wave 16384-bit LDS bitmap (9-word padded stripes), popcount+shfl-scan
// emits first SS ascending into ws (ushort). Conservative margins only ADD
// exactly-tested candidates; d2 matches numpy bit-exactly (fp contract off,
// (dx^2+dy^2)+dz^2 order) => absmax 0.
// --------------------------------------------------------------------------
__global__ __launch_bounds__(256) void ball_query_kernel(
    const float4* __restrict__ sorted4, const int* __restrict__ cellStart,
    const float* __restrict__ new_xyz, ushort* __restrict__ idxU) {
#pragma clang fp contract(off)
  __shared__ unsigned bmAll[4 * 576];  // 9216 B
  const int widx = threadIdx.x >> 6;
  const int lane = threadIdx.x & 63;
  const int wave = blockIdx.x * 4 + widx;
  const int b = wave >> 12;
  unsigned* bm = bmAll + widx * 576;
  ushort* myout = idxU + wave * SS;

  const float cx = new_xyz[wave * 3 + 0];
  const float cy = new_xyz[wave * 3 + 1];
  const float cz = new_xyz[wave * 3 + 2];
  const float4* __restrict__ sb = sorted4 + (size_t)b * NN;
  const int* __restrict__ csb = cellStart + b * 1001;

#pragma unroll
  for (int k = 0; k < 9; ++k) bm[k * 64 + lane] = 0;

  const float mg = 0.1f + 1e-5f;
  const int loy = cell_clamp_floor(cy - mg), hiy = cell_clamp_floor(cy + mg);
  const int loz = cell_clamp_floor(cz - mg), hiz = cell_clamp_floor(cz + mg);
  const int ny = hiy - loy + 1;
  const int nz = hiz - loz + 1;
  const int nr = nz * ny;  // 1..9 (z,y) rows

  int s_l = 0, len_l = 0;
  if (lane < nr) {
    int zi, yi;
    if (ny == 1) { zi = lane; yi = 0; }
    else if (ny == 2) { zi = lane >> 1; yi = lane & 1; }
    else { zi = (lane * 11) >> 5; yi = lane - zi * 3; }  // lane/3, lane<9
    const int zc = loz + zi, yc = loy + yi;
    const float y0 = yc * 0.1f, z0 = zc * 0.1f;
    const float dymin = fmaxf(fmaxf(y0 - cy, cy - (y0 + 0.1f)), 0.0f);
    const float dzmin = fmaxf(fmaxf(z0 - cz, cz - (z0 + 0.1f)), 0.0f);
    const float rem = mg * mg - dymin * dymin - dzmin * dzmin;
    if (rem > 0.0f) {
      const float dxa = sqrtf(rem) * 1.0000002f + 1e-7f;  // round-up guard
      const int lxr = cell_clamp_floor(cx - dxa);
      const int hxr = cell_clamp_floor(cx + dxa);
      const int c0 = (zc * GRES + yc) * GRES + lxr;
      s_l = csb[c0];
      len_l = csb[c0 + (hxr - lxr + 1)] - s_l;
    }
  }
  int incl = len_l;
#pragma unroll
  for (int d = 1; d <= 8; d <<= 1) {
    const int v = __shfl_up(incl, d);
    if (lane >= d) incl += v;
  }
  const int T = __shfl(incl, nr - 1);  // total candidates
  const int Lx = incl - len_l;

  int Lk[9], Sk[9];
#pragma unroll
  for (int k = 0; k < 9; ++k) {  // Lk[k] == T for k >= nr
    Lk[k] = __shfl(Lx, k);
    Sk[k] = __shfl(s_l, k);
  }

  auto flat_load = [&](int g) -> float4 {
    int L = Lk[0], S = Sk[0];
#pragma unroll
    for (int k = 1; k < 9; ++k) {
      const bool cge = g >= Lk[k];
      L = cge ? Lk[k] : L;
      S = cge ? Sk[k] : S;
    }
    return sb[S + (g - L)];
  };

  // 2-deep pipelined candidate loop
  const int nIt = (T + 63) >> 6;
  float4 cur = {};
  if (lane < T) cur = flat_load(lane);
  for (int it = 0; it < nIt; ++it) {
    float4 nxt = cur;
    const int gn = (it + 1) * 64 + lane;
    if (gn < T) nxt = flat_load(gn);
    const int g = it * 64 + lane;
    if (g < T) {
      const float dx = cx - cur.x;
      const float dy = cy - cur.y;
      const float dz = cz - cur.z;
      const float a = dx * dx + dy * dy;
      const float d2 = a + dz * dz;
      if (d2 < R2) {
        const int orig = __float_as_int(cur.w);
        const int wi = orig >> 5;  // word 0..511
        atomicOr(&bm[(wi >> 3) * 9 + (wi & 7)], 1u << (orig & 31));
      }
    }
    cur = nxt;
  }
  __threadfence_block();  // drain LDS atomics before the scan reads

  // Scan: lane l owns words [8l,8l+8) = orig indices [256l, 256l+256).
  unsigned wv[8];
  int c = 0;
  int fi = INT_MAX;
#pragma unroll
  for (int k = 0; k < 8; ++k) {
    wv[k] = bm[lane * 9 + k];
    c += (int)__popc(wv[k]);
    if (fi == INT_MAX && wv[k])
      fi = lane * 256 + k * 32 + (int)__builtin_ctz(wv[k]);
  }

  int incl2 = c;
#pragma unroll
  for (int d = 1; d < 64; d <<= 1) {
    const int t = __shfl_up(incl2, d);
    if (lane >= d) incl2 += t;
  }
  const int E = incl2 - c;              // exclusive prefix
  const int total = __shfl(incl2, 63);  // wave total in-ball count

  const unsigned long long nb = __ballot(c > 0);
  int fc = 0;
  if (nb) fc = __shfl(fi, (int)__builtin_ctzll(nb));

  int s = E;
  if (s < SS) {
#pragma unroll
    for (int k = 0; k < 8; ++k) {
      unsigned ww = wv[k];
      while (ww && s < SS) {
        const int bpos = (int)__builtin_ctz(ww);
        ww &= ww - 1;
        myout[s++] = (ushort)(lane * 256 + k * 32 + bpos);
      }
      if (s >= SS) break;
    }
  }
  for (int s2 = total + lane; s2 < SS; s2 += 64) myout[s2] = (ushort)fc;
}

// --------------------------------------------------------------------------
// D6: STANDALONE gather + group (R2/R3/R12-proven body, reps=1). idx from ws.
// --------------------------------------------------------------------------
__global__ __launch_bounds__(256) void group_kernel_t(
    const float* __restrict__ xyz, const float* __restrict__ new_xyz,
    const float* __restrict__ featT, const ushort* __restrict__ idxU,
    float* __restrict__ out) {
  __shared__ float lds[TILE * 65];
  __shared__ int idxsm[TILE];
  const int base = blockIdx.x * TILE;
  const int b = base >> 17;  // P*S = 2^17
  const int t = threadIdx.x;
  const size_t PS = (size_t)PP * SS;

  if (t < TILE) idxsm[t] = (int)idxU[base + t];
  __syncthreads();

  const float4* ftb = (const float4*)(featT + (size_t)b * NN * CC);
#pragma unroll
  for (int k = 0; k < 8; ++k) {
    const int u = k * 256 + t;  // [0, 2048)
    const int r = u >> 4;       // sample row 0..127
    const int q = u & 15;       // float4 within row
    const int v = idxsm[r];
    const float4 val = ftb[(size_t)v * 16 + q];
    float* dst = &lds[r * 65 + q * 4];
    dst[0] = val.x; dst[1] = val.y; dst[2] = val.z; dst[3] = val.w;
  }
  __syncthreads();

  if (t < TILE) {
    const int g = base + t;
    const int v = idxsm[t];
    const int p = (g >> 5) & (PP - 1);
    const float* xr = xyz + ((size_t)b * NN + v) * 3;
    const float* cr = new_xyz + (size_t)(b * PP + p) * 3;
    const size_t ob = (size_t)b * OUTCH * PS + ((size_t)g & (PS - 1));
    out[ob + 0 * PS] = xr[0] - cr[0];
    out[ob + 1 * PS] = xr[1] - cr[1];
    out[ob + 2 * PS] = xr[2] - cr[2];
  }

  float* ob3 = out + (size_t)b * OUTCH * PS + 3 * PS + ((size_t)base & (PS - 1));
#pragma unroll
  for (int k = 0; k < 32; ++k) {
    const int u = k * 256 + t;  // [0, 8192)
    const int c2 = u >> 7;      // channel 0..63
    const int r = u & 127;      // row 0..127
    ob3[(size_t)c2 * PS + r] = lds[r * 65 + c2];
  }
}

extern "C" void kernel_launch(void* const* d_in, const int* in_sizes, int n_in,
                              void* d_out, int out_size, void* d_ws, size_t ws_size,
                              hipStream_t stream) {
  const float* xyz = (const float*)d_in[0];
  const float* new_xyz = (const float*)d_in[1];
  const float* feat = (const float*)d_in[2];
  float* out = (float*)d_out;

  // ws layout (9.42 MB, R12-proven):
  //   [featT 8.39MB][sorted4 0.5MB][idxU 0.5MB][cellStart 8008B]
  //   [hist 8000B][fill 8000B][spare 32B]  (hist..spare = contiguous zero region)
  float* featT = (float*)d_ws;
  char* p = (char*)d_ws + (size_t)BB * NN * CC * sizeof(float);
  float4* sorted4 = (float4*)p;
  p += (size_t)BB * NN * sizeof(float4);
  ushort* idxU = (ushort*)p;
  p += (size_t)BB * PP * SS * sizeof(ushort);
  int* cellStart = (int*)p;
  p += (size_t)BB * 1001 * sizeof(int);
  int* hist = (int*)p;
  int* fill = hist + BB * NCELL;

  transpose_feat_kernel<<<dim3(NN / 64, BB), 256, 0, stream>>>(feat, featT, hist);
  hist_kernel<<<(BB * NN) / 256, 256, 0, stream>>>(xyz, hist);
  scan_fast_kernel<<<BB, 256, 0, stream>>>(hist, cellStart);
  scatter_kernel<<<(BB * NN) / 256, 256, 0, stream>>>(xyz, cellStart, fill, sorted4);
  ball_query_kernel<<<(BB * PP) / 4, 256, 0, stream>>>(sorted4, cellStart,
                                                       new_xyz, idxU);
  group_kernel_t<<<(BB * PP * SS) / TILE, 256, 0, stream>>>(xyz, new_xyz, featT,
                                                            idxU, out);
}